// Round 2
// baseline (329.590 us; speedup 1.0000x reference)
//
#include <hip/hip_runtime.h>
#include <math.h>

// TokenRouter: LN(x) -> silu(x @ Wd^T) -> @ Wu^T -> top2 softmax
// H=2048, D=64 (bottleneck), E=8, NTOK=4*4096=16384. All fp32.
//
// LN folded into GEMM:  dot_d = rstd*(A_d - mu*B_d) + C_d  where
//   A_d = sum_h x[h]*gamma[h]*Wd[d][h]   (the GEMM, per token)
//   B_d = sum_h gamma[h]*Wd[d][h]        (token-independent)
//   C_d = sum_h beta[h]*Wd[d][h]         (token-independent)
// mu/var accumulated during X staging; B/C during W staging.
//
// Tile: 64 tokens x 64 bottleneck per block, 256 threads, 4x4 microtile,
// K staged in chunks of 64. LDS rows padded to 68 floats (272B: 16B-aligned,
// worst-case 2-way bank aliasing which is free on gfx950).

#define H       2048
#define DBOT    64
#define NE      8
#define KC      64
#define NCHUNK  (H / KC)      // 32
#define LDSTR   68            // 64 + 4 pad

__global__ __launch_bounds__(256) void router_kernel(
    const float* __restrict__ X,      // [ntok][H]
    const float* __restrict__ Wd,     // [DBOT][H]
    const float* __restrict__ Wu,     // [NE][DBOT]
    const float* __restrict__ gamma,  // [H]
    const float* __restrict__ beta,   // [H]
    float* __restrict__ out,          // [ntok][NE]
    const int ntok)
{
    __shared__ float Xs[64 * LDSTR];
    __shared__ float Ws[64 * LDSTR];
    __shared__ float wuS[NE * DBOT];
    __shared__ float rsumS[64], rsqS[64], BdS[64], CdS[64];

    const int tid  = threadIdx.x;
    const int tx   = tid & 15;    // output col group (bottleneck dim)
    const int ty   = tid >> 4;    // output row group (token dim), 0..15
    const int f4c  = tid & 15;    // staging: float4 column within chunk
    const int rgrp = tid >> 4;    // staging: row within group of 16
    const long tok0 = (long)blockIdx.x * 64;

    // w_up -> LDS (512 floats = 128 float4)
    if (tid < 128) ((float4*)wuS)[tid] = ((const float4*)Wu)[tid];

    float acc[4][4];
    #pragma unroll
    for (int i = 0; i < 4; ++i)
        #pragma unroll
        for (int j = 0; j < 4; ++j) acc[i][j] = 0.0f;

    float xsum[4] = {0,0,0,0}, xsq[4] = {0,0,0,0};
    float bacc[4] = {0,0,0,0}, cacc[4] = {0,0,0,0};

    for (int ch = 0; ch < NCHUNK; ++ch) {
        const int k0 = ch * KC;
        __syncthreads();   // previous chunk's compute fully done before restage
        const float4 g4 = *(const float4*)&gamma[k0 + 4*f4c];
        const float4 b4 = *(const float4*)&beta [k0 + 4*f4c];
        #pragma unroll
        for (int p = 0; p < 4; ++p) {
            const int r = rgrp + 16*p;
            float4 xv = make_float4(0.f, 0.f, 0.f, 0.f);
            if (tok0 + r < ntok)
                xv = *(const float4*)&X[(tok0 + r)*(long)H + k0 + 4*f4c];
            *(float4*)&Xs[r*LDSTR + 4*f4c] = xv;
            xsum[p] += (xv.x + xv.y) + (xv.z + xv.w);
            xsq[p]  += (xv.x*xv.x + xv.y*xv.y) + (xv.z*xv.z + xv.w*xv.w);

            const float4 wv = *(const float4*)&Wd[r*(long)H + k0 + 4*f4c];
            const float4 wg = make_float4(wv.x*g4.x, wv.y*g4.y, wv.z*g4.z, wv.w*g4.w);
            *(float4*)&Ws[r*LDSTR + 4*f4c] = wg;
            bacc[p] += (wg.x + wg.y) + (wg.z + wg.w);
            cacc[p] += (wv.x*b4.x + wv.y*b4.y) + (wv.z*b4.z + wv.w*b4.w);
        }
        __syncthreads();

        #pragma unroll 4
        for (int kk = 0; kk < KC; kk += 4) {
            float4 xf[4], wf[4];
            #pragma unroll
            for (int i = 0; i < 4; ++i)
                xf[i] = *(const float4*)&Xs[(ty + 16*i)*LDSTR + kk];
            #pragma unroll
            for (int j = 0; j < 4; ++j)
                wf[j] = *(const float4*)&Ws[(tx + 16*j)*LDSTR + kk];
            #pragma unroll
            for (int i = 0; i < 4; ++i)
                #pragma unroll
                for (int j = 0; j < 4; ++j) {
                    acc[i][j] += xf[i].x * wf[j].x;
                    acc[i][j] += xf[i].y * wf[j].y;
                    acc[i][j] += xf[i].z * wf[j].z;
                    acc[i][j] += xf[i].w * wf[j].w;
                }
        }
    }

    // Reduce per-row stats across the 16 consecutive lanes sharing rgrp.
    // (tid>>4 is constant across lanes l, l^1, ..., l^15 for any group of
    //  16 consecutive lanes, in every wave.)
    #pragma unroll
    for (int p = 0; p < 4; ++p) {
        float s = xsum[p], q = xsq[p], b = bacc[p], c = cacc[p];
        #pragma unroll
        for (int m = 1; m < 16; m <<= 1) {
            s += __shfl_xor(s, m);
            q += __shfl_xor(q, m);
            b += __shfl_xor(b, m);
            c += __shfl_xor(c, m);
        }
        if (f4c == 0) {
            const int r = rgrp + 16*p;
            rsumS[r] = s; rsqS[r] = q; BdS[r] = b; CdS[r] = c;
        }
    }
    __syncthreads();

    // Epilogue 1: t = rstd*(A - mu*B) + C; z = silu(t) -> LDS (reuse Xs)
    const float invH = 1.0f / (float)H;
    #pragma unroll
    for (int i = 0; i < 4; ++i) {
        const int r = ty + 16*i;
        const float mu   = rsumS[r] * invH;
        const float var  = rsqS[r] * invH - mu*mu;
        const float rstd = 1.0f / sqrtf(var + 1e-5f);
        #pragma unroll
        for (int j = 0; j < 4; ++j) {
            const int c = tx + 16*j;
            const float t = rstd * (acc[i][j] - mu * BdS[c]) + CdS[c];
            Xs[r*LDSTR + c] = t / (1.0f + expf(-t));
        }
    }
    __syncthreads();

    // Epilogue 2: logits = z @ Wu^T, top-2 softmax, 8 floats/token.
    if (tid < 64 && tok0 + tid < ntok) {
        float lg[NE];
        #pragma unroll
        for (int e = 0; e < NE; ++e) lg[e] = 0.0f;
        #pragma unroll
        for (int dq = 0; dq < DBOT; dq += 4) {
            const float4 zv = *(const float4*)&Xs[tid*LDSTR + dq];
            #pragma unroll
            for (int e = 0; e < NE; ++e) {
                lg[e] += zv.x * wuS[e*DBOT + dq]
                       + zv.y * wuS[e*DBOT + dq + 1]
                       + zv.z * wuS[e*DBOT + dq + 2]
                       + zv.w * wuS[e*DBOT + dq + 3];
            }
        }
        // top-2; strict > keeps lowest index on ties (matches lax.top_k)
        float v1 = -INFINITY, v2 = -INFINITY;
        int i1 = -1, i2 = -1;
        #pragma unroll
        for (int e = 0; e < NE; ++e) {
            const float v = lg[e];
            if (v > v1)      { v2 = v1; i2 = i1; v1 = v; i1 = e; }
            else if (v > v2) { v2 = v;  i2 = e; }
        }
        const float e2  = expf(v2 - v1);
        const float inv = 1.0f / (1.0f + e2);
        float o[NE];
        #pragma unroll
        for (int e = 0; e < NE; ++e)
            o[e] = (e == i1) ? inv : ((e == i2) ? e2 * inv : 0.0f);
        float4* op = (float4*)&out[(tok0 + tid) * NE];
        op[0] = make_float4(o[0], o[1], o[2], o[3]);
        op[1] = make_float4(o[4], o[5], o[6], o[7]);
    }
}

extern "C" void kernel_launch(void* const* d_in, const int* in_sizes, int n_in,
                              void* d_out, int out_size, void* d_ws, size_t ws_size,
                              hipStream_t stream) {
    const float* X     = (const float*)d_in[0];  // hidden_states (4,4096,2048)
    const float* Wd    = (const float*)d_in[1];  // w_down (64,2048)
    const float* Wu    = (const float*)d_in[2];  // w_up (8,64)
    const float* gamma = (const float*)d_in[3];  // (2048,)
    const float* beta  = (const float*)d_in[4];  // (2048,)
    float* out = (float*)d_out;                  // (4,4096,8)

    const int ntok = in_sizes[0] / H;            // 16384
    const int nblk = (ntok + 63) / 64;           // 256

    hipLaunchKernelGGL(router_kernel, dim3(nblk), dim3(256), 0, stream,
                       X, Wd, Wu, gamma, beta, out, ntok);
}

// Round 3
// 306.786 us; speedup vs baseline: 1.0743x; 1.0743x over previous
//
#include <hip/hip_runtime.h>
#include <math.h>

// TokenRouter: LN(x) -> silu(x @ Wd^T) -> @ Wu^T -> top2 softmax
// H=2048, D=64 (bottleneck), E=8, NTOK=16384. All fp32 (no fp32 MFMA on CDNA4;
// bf16 MFMA rejected: logit sigma ~0.009, top-2 selection flips => absmax ~0.5).
//
// LN folded into GEMM:  dot_d = rstd*(A_d - mu*B_d) + C_d
//   A_d = sum_h x*gamma*Wd[d]  (GEMM)   B_d = sum_h gamma*Wd[d]   C_d = sum beta*Wd[d]
//
// R3: block-internal split-K=2. 512 threads = 2 halves x 256; each half owns
// half the K range with its own LDS X/W buffers (keeps the 4x4 microtile's
// 0.125 ds_read/FMA ratio) -> 8 waves/CU (2/SIMD, the max at VGPR~232),
// fixing the measured 11% occupancy / 26% VALUBusy latency exposure.

#define H       2048
#define DBOT    64
#define NE      8
#define KC      64
#define NCHUNK  16            // chunks per half (2 halves x 16 x 64 = 2048)
#define LDSTR   68            // 64 + 4 pad

__global__ __launch_bounds__(512) void router_kernel(
    const float* __restrict__ X,      // [ntok][H]
    const float* __restrict__ Wd,     // [DBOT][H]
    const float* __restrict__ Wu,     // [NE][DBOT]
    const float* __restrict__ gamma,  // [H]
    const float* __restrict__ beta,   // [H]
    float* __restrict__ out,          // [ntok][NE]
    const int ntok)
{
    __shared__ float Xs[2 * 64 * LDSTR];   // per-half X tiles (half 1 region reused as combine buf)
    __shared__ float Ws[2 * 64 * LDSTR];   // per-half gamma-folded W tiles
    __shared__ float wuS[NE * DBOT];
    __shared__ float rsumS[128], rsqS[128], BdS[128], CdS[128];  // [half][64]

    const int tid  = threadIdx.x;
    const int half = tid >> 8;      // 0 or 1: K-range owner
    const int htid = tid & 255;     // thread id within half
    const int tx   = htid & 15;     // output col group (bottleneck dim)
    const int ty   = htid >> 4;     // output row group (token dim), 0..15
    const int f4c  = htid & 15;     // staging: float4 column within chunk
    const int rgrp = htid >> 4;     // staging: row within group of 16
    const long tok0 = (long)blockIdx.x * 64;
    const int kbase = half * (H / 2);          // this half's K origin
    float* Xh = &Xs[half * 64 * LDSTR];
    float* Wh = &Ws[half * 64 * LDSTR];

    if (tid < 128) ((float4*)wuS)[tid] = ((const float4*)Wu)[tid];

    float acc[4][4];
    #pragma unroll
    for (int i = 0; i < 4; ++i)
        #pragma unroll
        for (int j = 0; j < 4; ++j) acc[i][j] = 0.0f;

    float xsum[4] = {0,0,0,0}, xsq[4] = {0,0,0,0};
    float bacc[4] = {0,0,0,0}, cacc[4] = {0,0,0,0};

    for (int ch = 0; ch < NCHUNK; ++ch) {
        const int k0 = kbase + ch * KC;
        __syncthreads();
        const float4 g4 = *(const float4*)&gamma[k0 + 4*f4c];
        const float4 b4 = *(const float4*)&beta [k0 + 4*f4c];
        #pragma unroll
        for (int p = 0; p < 4; ++p) {
            const int r = rgrp + 16*p;
            float4 xv = make_float4(0.f, 0.f, 0.f, 0.f);
            if (tok0 + r < ntok)
                xv = *(const float4*)&X[(tok0 + r)*(long)H + k0 + 4*f4c];
            *(float4*)&Xh[r*LDSTR + 4*f4c] = xv;
            xsum[p] += (xv.x + xv.y) + (xv.z + xv.w);
            xsq[p]  += (xv.x*xv.x + xv.y*xv.y) + (xv.z*xv.z + xv.w*xv.w);

            const float4 wv = *(const float4*)&Wd[r*(long)H + k0 + 4*f4c];
            const float4 wg = make_float4(wv.x*g4.x, wv.y*g4.y, wv.z*g4.z, wv.w*g4.w);
            *(float4*)&Wh[r*LDSTR + 4*f4c] = wg;
            bacc[p] += (wg.x + wg.y) + (wg.z + wg.w);
            cacc[p] += (wv.x*b4.x + wv.y*b4.y) + (wv.z*b4.z + wv.w*b4.w);
        }
        __syncthreads();

        #pragma unroll 4
        for (int kk = 0; kk < KC; kk += 4) {
            float4 xf[4], wf[4];
            #pragma unroll
            for (int i = 0; i < 4; ++i)
                xf[i] = *(const float4*)&Xh[(ty + 16*i)*LDSTR + kk];
            #pragma unroll
            for (int j = 0; j < 4; ++j)
                wf[j] = *(const float4*)&Wh[(tx + 16*j)*LDSTR + kk];
            #pragma unroll
            for (int i = 0; i < 4; ++i)
                #pragma unroll
                for (int j = 0; j < 4; ++j) {
                    acc[i][j] += xf[i].x * wf[j].x;
                    acc[i][j] += xf[i].y * wf[j].y;
                    acc[i][j] += xf[i].z * wf[j].z;
                    acc[i][j] += xf[i].w * wf[j].w;
                }
        }
    }

    // Per-half stats reduction across the 16 consecutive lanes sharing rgrp.
    #pragma unroll
    for (int p = 0; p < 4; ++p) {
        float s = xsum[p], q = xsq[p], b = bacc[p], c = cacc[p];
        #pragma unroll
        for (int m = 1; m < 16; m <<= 1) {
            s += __shfl_xor(s, m);
            q += __shfl_xor(q, m);
            b += __shfl_xor(b, m);
            c += __shfl_xor(c, m);
        }
        if (f4c == 0) {
            const int r = half*64 + rgrp + 16*p;
            rsumS[r] = s; rsqS[r] = q; BdS[r] = b; CdS[r] = c;
        }
    }
    __syncthreads();

    // Combine split-K partials: half 1 writes acc into Xs[1] region, half 0 adds.
    float* comb = &Xs[64 * LDSTR];   // 4096 floats needed, region is 4352
    if (half == 1) {
        #pragma unroll
        for (int i = 0; i < 4; ++i)
            *(float4*)&comb[htid*16 + i*4] =
                make_float4(acc[i][0], acc[i][1], acc[i][2], acc[i][3]);
    }
    __syncthreads();
    if (half == 0) {
        #pragma unroll
        for (int i = 0; i < 4; ++i) {
            const float4 a = *(const float4*)&comb[htid*16 + i*4];
            acc[i][0] += a.x; acc[i][1] += a.y; acc[i][2] += a.z; acc[i][3] += a.w;
        }
        // Epilogue 1: t = rstd*(A - mu*B) + C; z = silu(t) -> Xs[0] region
        const float invH = 1.0f / (float)H;
        #pragma unroll
        for (int i = 0; i < 4; ++i) {
            const int r = ty + 16*i;
            const float mu   = (rsumS[r] + rsumS[64+r]) * invH;
            const float var  = (rsqS[r] + rsqS[64+r]) * invH - mu*mu;
            const float rstd = 1.0f / sqrtf(var + 1e-5f);
            #pragma unroll
            for (int j = 0; j < 4; ++j) {
                const int c = tx + 16*j;
                const float t = rstd * (acc[i][j] - mu * (BdS[c] + CdS[64+c] - CdS[64+c] + BdS[64+c]))
                              + (CdS[c] + CdS[64+c]);
                Xs[r*LDSTR + c] = t / (1.0f + expf(-t));
            }
        }
    }
    __syncthreads();

    // Epilogue 2: logits = z @ Wu^T, top-2 softmax, 8 floats/token.
    if (tid < 64 && tok0 + tid < ntok) {
        float lg[NE];
        #pragma unroll
        for (int e = 0; e < NE; ++e) lg[e] = 0.0f;
        #pragma unroll
        for (int dq = 0; dq < DBOT; dq += 4) {
            const float4 zv = *(const float4*)&Xs[tid*LDSTR + dq];
            #pragma unroll
            for (int e = 0; e < NE; ++e) {
                lg[e] += zv.x * wuS[e*DBOT + dq]
                       + zv.y * wuS[e*DBOT + dq + 1]
                       + zv.z * wuS[e*DBOT + dq + 2]
                       + zv.w * wuS[e*DBOT + dq + 3];
            }
        }
        float v1 = -INFINITY, v2 = -INFINITY;
        int i1 = -1, i2 = -1;
        #pragma unroll
        for (int e = 0; e < NE; ++e) {
            const float v = lg[e];
            if (v > v1)      { v2 = v1; i2 = i1; v1 = v; i1 = e; }
            else if (v > v2) { v2 = v;  i2 = e; }
        }
        const float e2  = expf(v2 - v1);
        const float inv = 1.0f / (1.0f + e2);
        float o[NE];
        #pragma unroll
        for (int e = 0; e < NE; ++e)
            o[e] = (e == i1) ? inv : ((e == i2) ? e2 * inv : 0.0f);
        float4* op = (float4*)&out[(tok0 + tid) * NE];
        op[0] = make_float4(o[0], o[1], o[2], o[3]);
        op[1] = make_float4(o[4], o[5], o[6], o[7]);
    }
}

extern "C" void kernel_launch(void* const* d_in, const int* in_sizes, int n_in,
                              void* d_out, int out_size, void* d_ws, size_t ws_size,
                              hipStream_t stream) {
    const float* X     = (const float*)d_in[0];
    const float* Wd    = (const float*)d_in[1];
    const float* Wu    = (const float*)d_in[2];
    const float* gamma = (const float*)d_in[3];
    const float* beta  = (const float*)d_in[4];
    float* out = (float*)d_out;

    const int ntok = in_sizes[0] / H;            // 16384
    const int nblk = (ntok + 63) / 64;           // 256

    hipLaunchKernelGGL(router_kernel, dim3(nblk), dim3(512), 0, stream,
                       X, Wd, Wu, gamma, beta, out, ntok);
}